// Round 4
// baseline (289.810 us; speedup 1.0000x reference)
//
#include <hip/hip_runtime.h>
#include <hip/hip_bf16.h>

typedef __attribute__((ext_vector_type(8))) short bf16x8;
typedef __attribute__((ext_vector_type(4))) float floatx4;

constexpr int D_MODEL = 2048;
constexpr int N_HEADS = 32;
constexpr int N_KV    = 8;
constexpr int B_      = 2;
constexpr int T_      = 2048;
constexpr int BT      = B_ * T_;        // 4096
constexpr int NQKV    = 3072;           // 2048 Q + 512 K + 512 V

// Q pre-scale: 1/sqrt(64) * log2(e), folded into QKV-GEMM epilogue so the
// attention inner loop is a bare v_exp (p = 2^s).
constexpr float Q_SCALE = 0.18033688011112042f;

__device__ __forceinline__ unsigned short f2bf(float f) {
    __hip_bfloat16 h = __float2bfloat16(f);
    return *reinterpret_cast<unsigned short*>(&h);
}

// async 16B global->LDS; lds base wave-uniform, lane i lands at base + i*16.
__device__ __forceinline__ void gll16(const void* g, void* l) {
    typedef const __attribute__((address_space(1))) unsigned int* gp_t;
    typedef __attribute__((address_space(3))) unsigned int* lp_t;
    __builtin_amdgcn_global_load_lds((gp_t)g, (lp_t)l, 16, 0, 0);
}

// fused f32->bf16 of [x | Wq | Wk | Wv] into contiguous dst
__global__ __launch_bounds__(256) void cvt_all(
        const float* __restrict__ x,  const float* __restrict__ wq,
        const float* __restrict__ wk, const float* __restrict__ wv,
        unsigned short* __restrict__ dst) {
    size_t i4 = (size_t)blockIdx.x * 256 + threadIdx.x;
    size_t e = i4 * 4;
    const float* src; size_t off;
    if (e < 8388608)        { src = x;  off = 0; }
    else if (e < 12582912)  { src = wq; off = 8388608; }
    else if (e < 13631488)  { src = wk; off = 12582912; }
    else                    { src = wv; off = 13631488; }
    float4 f = *reinterpret_cast<const float4*>(src + (e - off));
    unsigned short u[4] = {f2bf(f.x), f2bf(f.y), f2bf(f.z), f2bf(f.w)};
    reinterpret_cast<uint2*>(dst)[i4] = *reinterpret_cast<const uint2*>(u);
}

__global__ __launch_bounds__(256) void cvt_bf16(
        const float* __restrict__ src, unsigned short* __restrict__ dst, int n4) {
    int i = blockIdx.x * 256 + threadIdx.x;
    if (i < n4) {
        float4 f = reinterpret_cast<const float4*>(src)[i];
        unsigned short u[4] = {f2bf(f.x), f2bf(f.y), f2bf(f.z), f2bf(f.w)};
        reinterpret_cast<uint2*>(dst)[i] = *reinterpret_cast<const uint2*>(u);
    }
}

// C[M,N] = A[M,K] @ B[N,K]^T, bf16 in, 128x128 tile, BK=64, XOR-swizzled LDS.
template<bool C_F32, bool SCALEQ>
__global__ __launch_bounds__(256) void gemm128(
        const unsigned short* __restrict__ A,
        const unsigned short* __restrict__ Bb,
        void* __restrict__ Cp,
        int M, int N, int K) {
    __shared__ unsigned short As[128 * 64];
    __shared__ unsigned short Bs[128 * 64];
    const int t = threadIdx.x;
    const int wave = t >> 6, lane = t & 63;
    const int l16 = lane & 15, quad = lane >> 4;
    const int wm = (wave & 1) * 64, wn = (wave >> 1) * 64;
    const int mtile = blockIdx.y * 128, ntile = blockIdx.x * 128;

    floatx4 acc[4][4] = {};

    for (int k0 = 0; k0 < K; k0 += 64) {
        __syncthreads();
#pragma unroll
        for (int c = 0; c < 4; c++) {
            int s = (c * 4 + wave) * 64 + lane;
            int row = s >> 3, k8 = (s & 7) ^ (row & 7);
            gll16(&A[(size_t)(mtile + row) * K + k0 + k8 * 8], &As[(c * 4 + wave) * 512]);
            gll16(&Bb[(size_t)(ntile + row) * K + k0 + k8 * 8], &Bs[(c * 4 + wave) * 512]);
        }
        __syncthreads();
#pragma unroll
        for (int kc = 0; kc < 2; kc++) {
            bf16x8 af[4], bfr[4];
#pragma unroll
            for (int i = 0; i < 4; i++) {
                int arow = wm + i * 16 + l16;
                af[i] = *reinterpret_cast<const bf16x8*>(
                    &As[(arow * 8 + ((kc * 4 + quad) ^ (arow & 7))) * 8]);
                int brow = wn + i * 16 + l16;
                bfr[i] = *reinterpret_cast<const bf16x8*>(
                    &Bs[(brow * 8 + ((kc * 4 + quad) ^ (brow & 7))) * 8]);
            }
#pragma unroll
            for (int i = 0; i < 4; i++)
#pragma unroll
                for (int jn = 0; jn < 4; jn++)
                    acc[i][jn] = __builtin_amdgcn_mfma_f32_16x16x32_bf16(
                        af[i], bfr[jn], acc[i][jn], 0, 0, 0);
        }
    }
    float cscale = (SCALEQ && ntile < 2048) ? Q_SCALE : 1.0f;
#pragma unroll
    for (int i = 0; i < 4; i++)
#pragma unroll
        for (int jn = 0; jn < 4; jn++)
#pragma unroll
            for (int r = 0; r < 4; r++) {
                int row = mtile + wm + i * 16 + quad * 4 + r;
                int col = ntile + wn + jn * 16 + l16;
                if constexpr (C_F32)
                    ((float*)Cp)[(size_t)row * N + col] = acc[i][jn][r];
                else
                    ((unsigned short*)Cp)[(size_t)row * N + col] =
                        f2bf(acc[i][jn][r] * cscale);
            }
}

// V columns of QKV -> Vt[bg][dim 64][token 2048]
__global__ __launch_bounds__(256) void vtrans(
        const unsigned short* __restrict__ QKV,
        unsigned short* __restrict__ Vt) {
    __shared__ unsigned short Ts[64][72];
    const int tb = blockIdx.x * 64;
    const int bg = blockIdx.y;
    const int b = bg >> 3, g = bg & 7;
    const int t = threadIdx.x;
#pragma unroll
    for (int it = 0; it < 2; it++) {
        int row = (t >> 3) + it * 32;
        int sl = t & 7;
        *reinterpret_cast<uint4*>(&Ts[row][sl * 8]) =
            *reinterpret_cast<const uint4*>(
                &QKV[(size_t)(b * T_ + tb + row) * NQKV + 2560 + g * 64 + sl * 8]);
    }
    __syncthreads();
#pragma unroll
    for (int it = 0; it < 2; it++) {
        int d = (t >> 3) + it * 32;
        int ks = t & 7;
        unsigned short u[8];
#pragma unroll
        for (int j = 0; j < 8; j++) u[j] = Ts[ks * 8 + j][d];
        *reinterpret_cast<uint4*>(&Vt[((size_t)bg * 64 + d) * T_ + tb + ks * 8]) =
            *reinterpret_cast<const uint4*>(u);
    }
}

// Flash causal GQA, occupancy-oriented: 64-q tiles (16 q-rows PER WAVE),
// grid (16, B*NH) = 1024 blocks (4 blocks/CU vs 2 before — the counters
// showed 20% occupancy, all pipes idle => latency-bound on grid TLP).
// Block does q-tiles j and 31-j sequentially -> uniform 33 key-tiles/block.
// Single-buffered K/V (dbuf was null at 2 blocks/CU and its LDS would cap
// blocks/CU at 3); scalar f2bf (m240: inline cvt_pk regressed 10%).
__global__ __launch_bounds__(256, 4) void attn6(
        const unsigned short* __restrict__ QKV,   // [4096][3072]
        const unsigned short* __restrict__ Vt,    // [16*64][2048]
        unsigned short* __restrict__ O) {         // [4096][2048]
    __shared__ unsigned short Ks[64 * 64];        // swizzled [key][dim]
    __shared__ unsigned short Vs[64 * 64];        // swizzled [dim][key]
    __shared__ unsigned short Ps[4][16 * 72];     // per-wave P, [q(16)][key 64]
    const int j  = blockIdx.x;                    // 0..15
    const int bh = blockIdx.y;
    const int b = bh >> 5, h = bh & 31;
    const int g = h >> 2;
    const int t = threadIdx.x, wave = t >> 6, lane = t & 63;
    const int l16 = lane & 15, quad = lane >> 4;

    bf16x8 ones;
#pragma unroll
    for (int i = 0; i < 8; i++) ones[i] = (short)0x3F80;   // bf16 1.0

    for (int pp = 0; pp < 2; pp++) {
        const int qtl = pp ? (31 - j) : j;
        const int q0  = qtl * 64;
        const int qlo = q0 + wave * 16;           // this wave's first q row

        const unsigned short* qptr =
            QKV + (size_t)(b * T_ + qlo + l16) * NQKV + h * 64;
        bf16x8 qf0 = *reinterpret_cast<const bf16x8*>(qptr + quad * 8);
        bf16x8 qf1 = *reinterpret_cast<const bf16x8*>(qptr + 32 + quad * 8);

        floatx4 o[4] = {};
        floatx4 lacc = {};

        const int nkt = qtl + 1;
        for (int kt = 0; kt < nkt; kt++) {
            const int kb = kt * 64;
            __syncthreads();
#pragma unroll
            for (int c = 0; c < 2; c++) {
                int s = (c * 4 + wave) * 64 + lane;
                int row = s >> 3, k8 = (s & 7) ^ (row & 7);
                gll16(&QKV[(size_t)(b * T_ + kb + row) * NQKV + 2048 + g * 64 + k8 * 8],
                      &Ks[(c * 4 + wave) * 512]);
                gll16(&Vt[((size_t)(b * 8 + g) * 64 + row) * T_ + kb + k8 * 8],
                      &Vs[(c * 4 + wave) * 512]);
            }
            __syncthreads();

            if (kb > qlo + 15) continue;          // no visible keys for this wave
            const bool needmask = (kb + 63 > qlo);

            // S^T per 16-key row-block; exp; pack into Ps
#pragma unroll
            for (int km = 0; km < 4; km++) {
                int krow = km * 16 + l16;
                bf16x8 k0 = *reinterpret_cast<const bf16x8*>(
                    &Ks[(krow * 8 + (quad ^ (krow & 7))) * 8]);
                bf16x8 k1 = *reinterpret_cast<const bf16x8*>(
                    &Ks[(krow * 8 + ((4 + quad) ^ (krow & 7))) * 8]);
                floatx4 z = {};
                __builtin_amdgcn_s_setprio(1);
                z = __builtin_amdgcn_mfma_f32_16x16x32_bf16(k0, qf0, z, 0, 0, 0);
                z = __builtin_amdgcn_mfma_f32_16x16x32_bf16(k1, qf1, z, 0, 0, 0);
                __builtin_amdgcn_s_setprio(0);
                unsigned short u[4];
                if (needmask) {
                    int qq = qlo + l16;
#pragma unroll
                    for (int r = 0; r < 4; r++) {
                        float p = __builtin_amdgcn_exp2f(z[r]);
                        if ((kb + km * 16 + quad * 4 + r) > qq) p = 0.f;
                        u[r] = f2bf(p);
                    }
                } else {
#pragma unroll
                    for (int r = 0; r < 4; r++)
                        u[r] = f2bf(__builtin_amdgcn_exp2f(z[r]));
                }
                *reinterpret_cast<uint2*>(
                    &Ps[wave][l16 * 72 + km * 16 + quad * 4]) =
                    *reinterpret_cast<const uint2*>(u);
            }

            // P fragments (A-layout), l-sum via MFMA, then PV
            bf16x8 pf[2];
            __builtin_amdgcn_s_setprio(1);
#pragma unroll
            for (int ks = 0; ks < 2; ks++)
                pf[ks] = *reinterpret_cast<const bf16x8*>(
                    &Ps[wave][l16 * 72 + ks * 32 + quad * 8]);
            lacc = __builtin_amdgcn_mfma_f32_16x16x32_bf16(pf[0], ones, lacc, 0, 0, 0);
            lacc = __builtin_amdgcn_mfma_f32_16x16x32_bf16(pf[1], ones, lacc, 0, 0, 0);
#pragma unroll
            for (int dt = 0; dt < 4; dt++) {
                int vrow = dt * 16 + l16;
                bf16x8 v0 = *reinterpret_cast<const bf16x8*>(
                    &Vs[(vrow * 8 + (quad ^ (vrow & 7))) * 8]);
                bf16x8 v1 = *reinterpret_cast<const bf16x8*>(
                    &Vs[(vrow * 8 + ((4 + quad) ^ (vrow & 7))) * 8]);
                o[dt] = __builtin_amdgcn_mfma_f32_16x16x32_bf16(pf[0], v0, o[dt], 0, 0, 0);
                o[dt] = __builtin_amdgcn_mfma_f32_16x16x32_bf16(pf[1], v1, o[dt], 0, 0, 0);
            }
            __builtin_amdgcn_s_setprio(0);
        }

        // epilogue
#pragma unroll
        for (int r = 0; r < 4; r++) {
            float inv = 1.0f / lacc[r];
            int row = b * T_ + qlo + quad * 4 + r;
#pragma unroll
            for (int dt = 0; dt < 4; dt++)
                O[(size_t)row * D_MODEL + h * 64 + dt * 16 + l16] =
                    f2bf(o[dt][r] * inv);
        }
    }
}

extern "C" void kernel_launch(void* const* d_in, const int* in_sizes, int n_in,
                              void* d_out, int out_size, void* d_ws, size_t ws_size,
                              hipStream_t stream) {
    const float* x  = (const float*)d_in[0];
    const float* Wq = (const float*)d_in[1];
    const float* Wk = (const float*)d_in[2];
    const float* Wv = (const float*)d_in[3];
    const float* Wo = (const float*)d_in[4];

    unsigned short* xb   = (unsigned short*)d_ws;             // [4096][2048]
    unsigned short* Wqkv = xb + (size_t)BT * D_MODEL;         // [3072][2048]
    unsigned short* QKVo = Wqkv + (size_t)NQKV * D_MODEL;     // [4096][3072]
    unsigned short* Vt   = QKVo + (size_t)BT * NQKV;          // [16][64][2048]
    unsigned short* Aw   = xb;                                 // reuse after QKV GEMM
    unsigned short* Wob  = Wqkv;                               // reuse after QKV GEMM

    dim3 blk(256);
    cvt_all<<<dim3(14336), blk, 0, stream>>>(x, Wq, Wk, Wv, xb);
    // fused QKV projection; Q columns pre-scaled by 1/8*log2(e)
    gemm128<false, true><<<dim3(NQKV / 128, BT / 128), blk, 0, stream>>>(
        xb, Wqkv, QKVo, BT, NQKV, D_MODEL);
    cvt_bf16<<<dim3(D_MODEL * D_MODEL / 4 / 256), blk, 0, stream>>>(
        Wo, Wob, D_MODEL * D_MODEL / 4);
    vtrans<<<dim3(T_ / 64, B_ * N_KV), blk, 0, stream>>>(QKVo, Vt);
    attn6<<<dim3(16, B_ * N_HEADS), blk, 0, stream>>>(QKVo, Vt, Aw);
    gemm128<true, false><<<dim3(D_MODEL / 128, BT / 128), blk, 0, stream>>>(
        Aw, Wob, d_out, BT, D_MODEL, D_MODEL);
}

// Round 5
// 288.665 us; speedup vs baseline: 1.0040x; 1.0040x over previous
//
#include <hip/hip_runtime.h>
#include <hip/hip_bf16.h>

typedef __attribute__((ext_vector_type(8))) short bf16x8;
typedef __attribute__((ext_vector_type(4))) float floatx4;

constexpr int D_MODEL = 2048;
constexpr int N_HEADS = 32;
constexpr int N_KV    = 8;
constexpr int B_      = 2;
constexpr int T_      = 2048;
constexpr int BT      = B_ * T_;        // 4096
constexpr int NQKV    = 3072;           // 2048 Q + 512 K + 512 V

// Q pre-scale: 1/sqrt(64) * log2(e), folded into QKV-GEMM epilogue so the
// attention inner loop is a bare v_exp (p = 2^s).
constexpr float Q_SCALE = 0.18033688011112042f;

__device__ __forceinline__ unsigned short f2bf(float f) {
    __hip_bfloat16 h = __float2bfloat16(f);
    return *reinterpret_cast<unsigned short*>(&h);
}

// cheap bf16 pack for values known finite & nonnegative (P = exp(s) in [0,1]):
// round-to-nearest (ties away) = (bits + 0x8000) >> 16. Two values -> 1 dword.
// Plain IR ops (no asm) so the scheduler can interleave with MFMA (R2 lesson:
// opaque inline-asm cvt_pk regressed 10% despite fewer instructions).
__device__ __forceinline__ unsigned bfpack_rn(float a, float b) {
    unsigned ba = __builtin_bit_cast(unsigned, a);
    unsigned bb = __builtin_bit_cast(unsigned, b);
    return ((ba + 0x8000u) >> 16) | ((bb + 0x8000u) & 0xFFFF0000u);
}

// async 16B global->LDS; lds base wave-uniform, lane i lands at base + i*16.
__device__ __forceinline__ void gll16(const void* g, void* l) {
    typedef const __attribute__((address_space(1))) unsigned int* gp_t;
    typedef __attribute__((address_space(3))) unsigned int* lp_t;
    __builtin_amdgcn_global_load_lds((gp_t)g, (lp_t)l, 16, 0, 0);
}

// fused f32->bf16 of [x | Wq | Wk | Wv] into contiguous dst
__global__ __launch_bounds__(256) void cvt_all(
        const float* __restrict__ x,  const float* __restrict__ wq,
        const float* __restrict__ wk, const float* __restrict__ wv,
        unsigned short* __restrict__ dst) {
    size_t i4 = (size_t)blockIdx.x * 256 + threadIdx.x;
    size_t e = i4 * 4;
    const float* src; size_t off;
    if (e < 8388608)        { src = x;  off = 0; }
    else if (e < 12582912)  { src = wq; off = 8388608; }
    else if (e < 13631488)  { src = wk; off = 12582912; }
    else                    { src = wv; off = 13631488; }
    float4 f = *reinterpret_cast<const float4*>(src + (e - off));
    unsigned short u[4] = {f2bf(f.x), f2bf(f.y), f2bf(f.z), f2bf(f.w)};
    reinterpret_cast<uint2*>(dst)[i4] = *reinterpret_cast<const uint2*>(u);
}

__global__ __launch_bounds__(256) void cvt_bf16(
        const float* __restrict__ src, unsigned short* __restrict__ dst, int n4) {
    int i = blockIdx.x * 256 + threadIdx.x;
    if (i < n4) {
        float4 f = reinterpret_cast<const float4*>(src)[i];
        unsigned short u[4] = {f2bf(f.x), f2bf(f.y), f2bf(f.z), f2bf(f.w)};
        reinterpret_cast<uint2*>(dst)[i] = *reinterpret_cast<const uint2*>(u);
    }
}

// C[M,N] = A[M,K] @ B[N,K]^T, bf16 in, 128x128 tile, BK=64, XOR-swizzled LDS.
template<bool C_F32, bool SCALEQ>
__global__ __launch_bounds__(256) void gemm128(
        const unsigned short* __restrict__ A,
        const unsigned short* __restrict__ Bb,
        void* __restrict__ Cp,
        int M, int N, int K) {
    __shared__ unsigned short As[128 * 64];
    __shared__ unsigned short Bs[128 * 64];
    const int t = threadIdx.x;
    const int wave = t >> 6, lane = t & 63;
    const int l16 = lane & 15, quad = lane >> 4;
    const int wm = (wave & 1) * 64, wn = (wave >> 1) * 64;
    const int mtile = blockIdx.y * 128, ntile = blockIdx.x * 128;

    floatx4 acc[4][4] = {};

    for (int k0 = 0; k0 < K; k0 += 64) {
        __syncthreads();
#pragma unroll
        for (int c = 0; c < 4; c++) {
            int s = (c * 4 + wave) * 64 + lane;
            int row = s >> 3, k8 = (s & 7) ^ (row & 7);
            gll16(&A[(size_t)(mtile + row) * K + k0 + k8 * 8], &As[(c * 4 + wave) * 512]);
            gll16(&Bb[(size_t)(ntile + row) * K + k0 + k8 * 8], &Bs[(c * 4 + wave) * 512]);
        }
        __syncthreads();
#pragma unroll
        for (int kc = 0; kc < 2; kc++) {
            bf16x8 af[4], bfr[4];
#pragma unroll
            for (int i = 0; i < 4; i++) {
                int arow = wm + i * 16 + l16;
                af[i] = *reinterpret_cast<const bf16x8*>(
                    &As[(arow * 8 + ((kc * 4 + quad) ^ (arow & 7))) * 8]);
                int brow = wn + i * 16 + l16;
                bfr[i] = *reinterpret_cast<const bf16x8*>(
                    &Bs[(brow * 8 + ((kc * 4 + quad) ^ (brow & 7))) * 8]);
            }
#pragma unroll
            for (int i = 0; i < 4; i++)
#pragma unroll
                for (int jn = 0; jn < 4; jn++)
                    acc[i][jn] = __builtin_amdgcn_mfma_f32_16x16x32_bf16(
                        af[i], bfr[jn], acc[i][jn], 0, 0, 0);
        }
    }
    float cscale = (SCALEQ && ntile < 2048) ? Q_SCALE : 1.0f;
#pragma unroll
    for (int i = 0; i < 4; i++)
#pragma unroll
        for (int jn = 0; jn < 4; jn++)
#pragma unroll
            for (int r = 0; r < 4; r++) {
                int row = mtile + wm + i * 16 + quad * 4 + r;
                int col = ntile + wn + jn * 16 + l16;
                if constexpr (C_F32)
                    ((float*)Cp)[(size_t)row * N + col] = acc[i][jn][r];
                else
                    ((unsigned short*)Cp)[(size_t)row * N + col] =
                        f2bf(acc[i][jn][r] * cscale);
            }
}

// V columns of QKV -> Vt[bg][dim 64][token 2048]
__global__ __launch_bounds__(256) void vtrans(
        const unsigned short* __restrict__ QKV,
        unsigned short* __restrict__ Vt) {
    __shared__ unsigned short Ts[64][72];
    const int tb = blockIdx.x * 64;
    const int bg = blockIdx.y;
    const int b = bg >> 3, g = bg & 7;
    const int t = threadIdx.x;
#pragma unroll
    for (int it = 0; it < 2; it++) {
        int row = (t >> 3) + it * 32;
        int sl = t & 7;
        *reinterpret_cast<uint4*>(&Ts[row][sl * 8]) =
            *reinterpret_cast<const uint4*>(
                &QKV[(size_t)(b * T_ + tb + row) * NQKV + 2560 + g * 64 + sl * 8]);
    }
    __syncthreads();
#pragma unroll
    for (int it = 0; it < 2; it++) {
        int d = (t >> 3) + it * 32;
        int ks = t & 7;
        unsigned short u[8];
#pragma unroll
        for (int j = 0; j < 8; j++) u[j] = Ts[ks * 8 + j][d];
        *reinterpret_cast<uint4*>(&Vt[((size_t)bg * 64 + d) * T_ + tb + ks * 8]) =
            *reinterpret_cast<const uint4*>(u);
    }
}

// Flash causal GQA, 64-q tiles (16 q-rows per wave), grid (16, B*NH) = 1024
// blocks. Block does q-tiles j and 31-j sequentially -> uniform 33 key-tiles.
// R4 counters: VALUBusy 40% / MfmaUtil 24% -> ~120 VALU inst per wave-tile,
// dominated by 16x library __float2bfloat16 (RNE + NaN path, ~5-6 inst each).
// P is exp() output: finite, >=0 -> use 3-5-inst round-nearest pack instead.
__global__ __launch_bounds__(256, 4) void attn6(
        const unsigned short* __restrict__ QKV,   // [4096][3072]
        const unsigned short* __restrict__ Vt,    // [16*64][2048]
        unsigned short* __restrict__ O) {         // [4096][2048]
    __shared__ unsigned short Ks[64 * 64];        // swizzled [key][dim]
    __shared__ unsigned short Vs[64 * 64];        // swizzled [dim][key]
    __shared__ unsigned short Ps[4][16 * 72];     // per-wave P, [q(16)][key 64]
    const int j  = blockIdx.x;                    // 0..15
    const int bh = blockIdx.y;
    const int b = bh >> 5, h = bh & 31;
    const int g = h >> 2;
    const int t = threadIdx.x, wave = t >> 6, lane = t & 63;
    const int l16 = lane & 15, quad = lane >> 4;

    bf16x8 ones;
#pragma unroll
    for (int i = 0; i < 8; i++) ones[i] = (short)0x3F80;   // bf16 1.0

    for (int pp = 0; pp < 2; pp++) {
        const int qtl = pp ? (31 - j) : j;
        const int q0  = qtl * 64;
        const int qlo = q0 + wave * 16;           // this wave's first q row

        const unsigned short* qptr =
            QKV + (size_t)(b * T_ + qlo + l16) * NQKV + h * 64;
        bf16x8 qf0 = *reinterpret_cast<const bf16x8*>(qptr + quad * 8);
        bf16x8 qf1 = *reinterpret_cast<const bf16x8*>(qptr + 32 + quad * 8);

        floatx4 o[4] = {};
        floatx4 lacc = {};

        const int nkt = qtl + 1;
        for (int kt = 0; kt < nkt; kt++) {
            const int kb = kt * 64;
            __syncthreads();
#pragma unroll
            for (int c = 0; c < 2; c++) {
                int s = (c * 4 + wave) * 64 + lane;
                int row = s >> 3, k8 = (s & 7) ^ (row & 7);
                gll16(&QKV[(size_t)(b * T_ + kb + row) * NQKV + 2048 + g * 64 + k8 * 8],
                      &Ks[(c * 4 + wave) * 512]);
                gll16(&Vt[((size_t)(b * 8 + g) * 64 + row) * T_ + kb + k8 * 8],
                      &Vs[(c * 4 + wave) * 512]);
            }
            __syncthreads();

            if (kb > qlo + 15) continue;          // no visible keys for this wave
            const bool needmask = (kb + 63 > qlo);

            // S^T per 16-key row-block; exp; pack into Ps
#pragma unroll
            for (int km = 0; km < 4; km++) {
                int krow = km * 16 + l16;
                bf16x8 k0 = *reinterpret_cast<const bf16x8*>(
                    &Ks[(krow * 8 + (quad ^ (krow & 7))) * 8]);
                bf16x8 k1 = *reinterpret_cast<const bf16x8*>(
                    &Ks[(krow * 8 + ((4 + quad) ^ (krow & 7))) * 8]);
                floatx4 z = {};
                __builtin_amdgcn_s_setprio(1);
                z = __builtin_amdgcn_mfma_f32_16x16x32_bf16(k0, qf0, z, 0, 0, 0);
                z = __builtin_amdgcn_mfma_f32_16x16x32_bf16(k1, qf1, z, 0, 0, 0);
                __builtin_amdgcn_s_setprio(0);
                float p[4];
#pragma unroll
                for (int r = 0; r < 4; r++)
                    p[r] = __builtin_amdgcn_exp2f(z[r]);
                if (needmask) {
                    int qq = qlo + l16;
#pragma unroll
                    for (int r = 0; r < 4; r++)
                        if ((kb + km * 16 + quad * 4 + r) > qq) p[r] = 0.f;
                }
                uint2 w;
                w.x = bfpack_rn(p[0], p[1]);
                w.y = bfpack_rn(p[2], p[3]);
                *reinterpret_cast<uint2*>(
                    &Ps[wave][l16 * 72 + km * 16 + quad * 4]) = w;
            }

            // P fragments (A-layout), l-sum via MFMA, then PV
            bf16x8 pf[2];
            __builtin_amdgcn_s_setprio(1);
#pragma unroll
            for (int ks = 0; ks < 2; ks++)
                pf[ks] = *reinterpret_cast<const bf16x8*>(
                    &Ps[wave][l16 * 72 + ks * 32 + quad * 8]);
            lacc = __builtin_amdgcn_mfma_f32_16x16x32_bf16(pf[0], ones, lacc, 0, 0, 0);
            lacc = __builtin_amdgcn_mfma_f32_16x16x32_bf16(pf[1], ones, lacc, 0, 0, 0);
#pragma unroll
            for (int dt = 0; dt < 4; dt++) {
                int vrow = dt * 16 + l16;
                bf16x8 v0 = *reinterpret_cast<const bf16x8*>(
                    &Vs[(vrow * 8 + (quad ^ (vrow & 7))) * 8]);
                bf16x8 v1 = *reinterpret_cast<const bf16x8*>(
                    &Vs[(vrow * 8 + ((4 + quad) ^ (vrow & 7))) * 8]);
                o[dt] = __builtin_amdgcn_mfma_f32_16x16x32_bf16(pf[0], v0, o[dt], 0, 0, 0);
                o[dt] = __builtin_amdgcn_mfma_f32_16x16x32_bf16(pf[1], v1, o[dt], 0, 0, 0);
            }
            __builtin_amdgcn_s_setprio(0);
        }

        // epilogue
#pragma unroll
        for (int r = 0; r < 4; r++) {
            float inv = 1.0f / lacc[r];
            int row = b * T_ + qlo + quad * 4 + r;
#pragma unroll
            for (int dt = 0; dt < 4; dt++)
                O[(size_t)row * D_MODEL + h * 64 + dt * 16 + l16] =
                    f2bf(o[dt][r] * inv);
        }
    }
}

extern "C" void kernel_launch(void* const* d_in, const int* in_sizes, int n_in,
                              void* d_out, int out_size, void* d_ws, size_t ws_size,
                              hipStream_t stream) {
    const float* x  = (const float*)d_in[0];
    const float* Wq = (const float*)d_in[1];
    const float* Wk = (const float*)d_in[2];
    const float* Wv = (const float*)d_in[3];
    const float* Wo = (const float*)d_in[4];

    unsigned short* xb   = (unsigned short*)d_ws;             // [4096][2048]
    unsigned short* Wqkv = xb + (size_t)BT * D_MODEL;         // [3072][2048]
    unsigned short* QKVo = Wqkv + (size_t)NQKV * D_MODEL;     // [4096][3072]
    unsigned short* Vt   = QKVo + (size_t)BT * NQKV;          // [16][64][2048]
    unsigned short* Aw   = xb;                                 // reuse after QKV GEMM
    unsigned short* Wob  = Wqkv;                               // reuse after QKV GEMM

    dim3 blk(256);
    cvt_all<<<dim3(14336), blk, 0, stream>>>(x, Wq, Wk, Wv, xb);
    // fused QKV projection; Q columns pre-scaled by 1/8*log2(e)
    gemm128<false, true><<<dim3(NQKV / 128, BT / 128), blk, 0, stream>>>(
        xb, Wqkv, QKVo, BT, NQKV, D_MODEL);
    cvt_bf16<<<dim3(D_MODEL * D_MODEL / 4 / 256), blk, 0, stream>>>(
        Wo, Wob, D_MODEL * D_MODEL / 4);
    vtrans<<<dim3(T_ / 64, B_ * N_KV), blk, 0, stream>>>(QKVo, Vt);
    attn6<<<dim3(16, B_ * N_HEADS), blk, 0, stream>>>(QKVo, Vt, Aw);
    gemm128<true, false><<<dim3(D_MODEL / 128, BT / 128), blk, 0, stream>>>(
        Aw, Wob, d_out, BT, D_MODEL, D_MODEL);
}

// Round 6
// 272.789 us; speedup vs baseline: 1.0624x; 1.0582x over previous
//
#include <hip/hip_runtime.h>
#include <hip/hip_bf16.h>

typedef __attribute__((ext_vector_type(8))) short bf16x8;
typedef __attribute__((ext_vector_type(4))) float floatx4;

constexpr int D_MODEL = 2048;
constexpr int N_HEADS = 32;
constexpr int N_KV    = 8;
constexpr int B_      = 2;
constexpr int T_      = 2048;
constexpr int BT      = B_ * T_;        // 4096
constexpr int NQKV    = 3072;           // 2048 Q + 512 K + 512 V

// Q pre-scale: 1/sqrt(64) * log2(e), folded into QKV-GEMM epilogue so the
// attention inner loop is a bare v_exp (p = 2^s).
constexpr float Q_SCALE = 0.18033688011112042f;

__device__ __forceinline__ unsigned short f2bf(float f) {
    __hip_bfloat16 h = __float2bfloat16(f);
    return *reinterpret_cast<unsigned short*>(&h);
}

// cheap bf16 pack for values known finite & nonnegative (P = exp(s) in [0,1]):
// round-to-nearest (ties away) = (bits + 0x8000) >> 16. Two values -> 1 dword.
__device__ __forceinline__ unsigned bfpack_rn(float a, float b) {
    unsigned ba = __builtin_bit_cast(unsigned, a);
    unsigned bb = __builtin_bit_cast(unsigned, b);
    return ((ba + 0x8000u) >> 16) | ((bb + 0x8000u) & 0xFFFF0000u);
}

// async 16B global->LDS; lds base wave-uniform, lane i lands at base + i*16.
__device__ __forceinline__ void gll16(const void* g, void* l) {
    typedef const __attribute__((address_space(1))) unsigned int* gp_t;
    typedef __attribute__((address_space(3))) unsigned int* lp_t;
    __builtin_amdgcn_global_load_lds((gp_t)g, (lp_t)l, 16, 0, 0);
}

// fused f32->bf16 of [x | Wq | Wk | Wv] into contiguous dst
__global__ __launch_bounds__(256) void cvt_all(
        const float* __restrict__ x,  const float* __restrict__ wq,
        const float* __restrict__ wk, const float* __restrict__ wv,
        unsigned short* __restrict__ dst) {
    size_t i4 = (size_t)blockIdx.x * 256 + threadIdx.x;
    size_t e = i4 * 4;
    const float* src; size_t off;
    if (e < 8388608)        { src = x;  off = 0; }
    else if (e < 12582912)  { src = wq; off = 8388608; }
    else if (e < 13631488)  { src = wk; off = 12582912; }
    else                    { src = wv; off = 13631488; }
    float4 f = *reinterpret_cast<const float4*>(src + (e - off));
    unsigned short u[4] = {f2bf(f.x), f2bf(f.y), f2bf(f.z), f2bf(f.w)};
    reinterpret_cast<uint2*>(dst)[i4] = *reinterpret_cast<const uint2*>(u);
}

__global__ __launch_bounds__(256) void cvt_bf16(
        const float* __restrict__ src, unsigned short* __restrict__ dst, int n4) {
    int i = blockIdx.x * 256 + threadIdx.x;
    if (i < n4) {
        float4 f = reinterpret_cast<const float4*>(src)[i];
        unsigned short u[4] = {f2bf(f.x), f2bf(f.y), f2bf(f.z), f2bf(f.w)};
        reinterpret_cast<uint2*>(dst)[i] = *reinterpret_cast<const uint2*>(u);
    }
}

// C[M,N] = A[M,K] @ B[N,K]^T, bf16 in, 128x128 tile, BK=64, XOR-swizzled LDS.
template<bool C_F32, bool SCALEQ>
__global__ __launch_bounds__(256) void gemm128(
        const unsigned short* __restrict__ A,
        const unsigned short* __restrict__ Bb,
        void* __restrict__ Cp,
        int M, int N, int K) {
    __shared__ unsigned short As[128 * 64];
    __shared__ unsigned short Bs[128 * 64];
    const int t = threadIdx.x;
    const int wave = t >> 6, lane = t & 63;
    const int l16 = lane & 15, quad = lane >> 4;
    const int wm = (wave & 1) * 64, wn = (wave >> 1) * 64;
    const int mtile = blockIdx.y * 128, ntile = blockIdx.x * 128;

    floatx4 acc[4][4] = {};

    for (int k0 = 0; k0 < K; k0 += 64) {
        __syncthreads();
#pragma unroll
        for (int c = 0; c < 4; c++) {
            int s = (c * 4 + wave) * 64 + lane;
            int row = s >> 3, k8 = (s & 7) ^ (row & 7);
            gll16(&A[(size_t)(mtile + row) * K + k0 + k8 * 8], &As[(c * 4 + wave) * 512]);
            gll16(&Bb[(size_t)(ntile + row) * K + k0 + k8 * 8], &Bs[(c * 4 + wave) * 512]);
        }
        __syncthreads();
#pragma unroll
        for (int kc = 0; kc < 2; kc++) {
            bf16x8 af[4], bfr[4];
#pragma unroll
            for (int i = 0; i < 4; i++) {
                int arow = wm + i * 16 + l16;
                af[i] = *reinterpret_cast<const bf16x8*>(
                    &As[(arow * 8 + ((kc * 4 + quad) ^ (arow & 7))) * 8]);
                int brow = wn + i * 16 + l16;
                bfr[i] = *reinterpret_cast<const bf16x8*>(
                    &Bs[(brow * 8 + ((kc * 4 + quad) ^ (brow & 7))) * 8]);
            }
#pragma unroll
            for (int i = 0; i < 4; i++)
#pragma unroll
                for (int jn = 0; jn < 4; jn++)
                    acc[i][jn] = __builtin_amdgcn_mfma_f32_16x16x32_bf16(
                        af[i], bfr[jn], acc[i][jn], 0, 0, 0);
        }
    }
    float cscale = (SCALEQ && ntile < 2048) ? Q_SCALE : 1.0f;
#pragma unroll
    for (int i = 0; i < 4; i++)
#pragma unroll
        for (int jn = 0; jn < 4; jn++)
#pragma unroll
            for (int r = 0; r < 4; r++) {
                int row = mtile + wm + i * 16 + quad * 4 + r;
                int col = ntile + wn + jn * 16 + l16;
                if constexpr (C_F32)
                    ((float*)Cp)[(size_t)row * N + col] = acc[i][jn][r];
                else
                    ((unsigned short*)Cp)[(size_t)row * N + col] =
                        f2bf(acc[i][jn][r] * cscale);
            }
}

// V columns of QKV -> Vt[bg][dim 64][token 2048]
__global__ __launch_bounds__(256) void vtrans(
        const unsigned short* __restrict__ QKV,
        unsigned short* __restrict__ Vt) {
    __shared__ unsigned short Ts[64][72];
    const int tb = blockIdx.x * 64;
    const int bg = blockIdx.y;
    const int b = bg >> 3, g = bg & 7;
    const int t = threadIdx.x;
#pragma unroll
    for (int it = 0; it < 2; it++) {
        int row = (t >> 3) + it * 32;
        int sl = t & 7;
        *reinterpret_cast<uint4*>(&Ts[row][sl * 8]) =
            *reinterpret_cast<const uint4*>(
                &QKV[(size_t)(b * T_ + tb + row) * NQKV + 2560 + g * 64 + sl * 8]);
    }
    __syncthreads();
#pragma unroll
    for (int it = 0; it < 2; it++) {
        int d = (t >> 3) + it * 32;
        int ks = t & 7;
        unsigned short u[8];
#pragma unroll
        for (int j = 0; j < 8; j++) u[j] = Ts[ks * 8 + j][d];
        *reinterpret_cast<uint4*>(&Vt[((size_t)bg * 64 + d) * T_ + tb + ks * 8]) =
            *reinterpret_cast<const uint4*>(u);
    }
}

// Flash causal GQA, staging-amortized: 512-thread blocks (8 waves), 128-q
// tile, 16 q-rows PER WAVE. Cross-round evidence: attn5 (4w, 128-q, 512
// blocks) and attn6 (4w, 64-q, 1024 blocks) tie at ~68us — doubled occupancy
// was cancelled by doubled K/V staging (FETCH 40.6->49.9 GB). This shape
// keeps attn6's 16 waves/CU (512 blocks x 2/CU x 8 waves) but amortizes one
// staging over 8 waves: 2 gll16/wave/tile instead of 4, K/V HBM re-fetch
// halved. Block does q-tiles j and 15-j sequentially -> uniform 34 kt/block.
__global__ __launch_bounds__(512, 4) void attn7(
        const unsigned short* __restrict__ QKV,   // [4096][3072]
        const unsigned short* __restrict__ Vt,    // [16*64][2048]
        unsigned short* __restrict__ O) {         // [4096][2048]
    __shared__ unsigned short Ks[64 * 64];        // swizzled [key][dim]
    __shared__ unsigned short Vs[64 * 64];        // swizzled [dim][key]
    __shared__ unsigned short Ps[8][16 * 72];     // per-wave P, [q(16)][key 64]
    const int j  = blockIdx.x;                    // 0..7
    const int bh = blockIdx.y;
    const int b = bh >> 5, h = bh & 31;
    const int g = h >> 2;
    const int t = threadIdx.x, wave = t >> 6, lane = t & 63;
    const int l16 = lane & 15, quad = lane >> 4;

    bf16x8 ones;
#pragma unroll
    for (int i = 0; i < 8; i++) ones[i] = (short)0x3F80;   // bf16 1.0

    // per-thread staging source (512 threads cover one 64x64 K tile + V tile)
    const int srow = t >> 3;                      // 0..63
    const int sk8  = (t & 7) ^ (srow & 7);        // XOR-swizzled 8-short slot
    const unsigned short* kbase =
        QKV + (size_t)(b * T_ + srow) * NQKV + 2048 + g * 64 + sk8 * 8;
    const unsigned short* vbase =
        Vt + ((size_t)(b * 8 + g) * 64 + srow) * T_ + sk8 * 8;
    unsigned short* kdst = &Ks[wave * 512];
    unsigned short* vdst = &Vs[wave * 512];

    for (int pp = 0; pp < 2; pp++) {
        const int qtl = pp ? (15 - j) : j;
        const int q0  = qtl * 128;
        const int qlo = q0 + wave * 16;           // this wave's first q row

        const unsigned short* qptr =
            QKV + (size_t)(b * T_ + qlo + l16) * NQKV + h * 64;
        bf16x8 qf0 = *reinterpret_cast<const bf16x8*>(qptr + quad * 8);
        bf16x8 qf1 = *reinterpret_cast<const bf16x8*>(qptr + 32 + quad * 8);

        floatx4 o[4] = {};
        floatx4 lacc = {};

        const unsigned short* kp = kbase;         // advances 64 keys per kt
        const unsigned short* vp = vbase;         // advances 64 tokens per kt

        const int nkt = 2 * qtl + 2;
        for (int kt = 0; kt < nkt; kt++) {
            const int kb = kt * 64;
            __syncthreads();
            gll16(kp, kdst);
            gll16(vp, vdst);
            kp += 64 * NQKV;
            vp += 64;
            __syncthreads();

            if (kb > qlo + 15) continue;          // no visible keys for this wave
            const bool needmask = (kb + 63 > qlo);

            // S^T per 16-key row-block; exp; pack into Ps
#pragma unroll
            for (int km = 0; km < 4; km++) {
                int krow = km * 16 + l16;
                bf16x8 k0 = *reinterpret_cast<const bf16x8*>(
                    &Ks[(krow * 8 + (quad ^ (krow & 7))) * 8]);
                bf16x8 k1 = *reinterpret_cast<const bf16x8*>(
                    &Ks[(krow * 8 + ((4 + quad) ^ (krow & 7))) * 8]);
                floatx4 z = {};
                __builtin_amdgcn_s_setprio(1);
                z = __builtin_amdgcn_mfma_f32_16x16x32_bf16(k0, qf0, z, 0, 0, 0);
                z = __builtin_amdgcn_mfma_f32_16x16x32_bf16(k1, qf1, z, 0, 0, 0);
                __builtin_amdgcn_s_setprio(0);
                float p[4];
#pragma unroll
                for (int r = 0; r < 4; r++)
                    p[r] = __builtin_amdgcn_exp2f(z[r]);
                if (needmask) {
                    int qq = qlo + l16;
#pragma unroll
                    for (int r = 0; r < 4; r++)
                        if ((kb + km * 16 + quad * 4 + r) > qq) p[r] = 0.f;
                }
                uint2 w;
                w.x = bfpack_rn(p[0], p[1]);
                w.y = bfpack_rn(p[2], p[3]);
                *reinterpret_cast<uint2*>(
                    &Ps[wave][l16 * 72 + km * 16 + quad * 4]) = w;
            }

            // P fragments (A-layout), l-sum via MFMA, then PV
            bf16x8 pf[2];
            __builtin_amdgcn_s_setprio(1);
#pragma unroll
            for (int ks = 0; ks < 2; ks++)
                pf[ks] = *reinterpret_cast<const bf16x8*>(
                    &Ps[wave][l16 * 72 + ks * 32 + quad * 8]);
            lacc = __builtin_amdgcn_mfma_f32_16x16x32_bf16(pf[0], ones, lacc, 0, 0, 0);
            lacc = __builtin_amdgcn_mfma_f32_16x16x32_bf16(pf[1], ones, lacc, 0, 0, 0);
#pragma unroll
            for (int dt = 0; dt < 4; dt++) {
                int vrow = dt * 16 + l16;
                bf16x8 v0 = *reinterpret_cast<const bf16x8*>(
                    &Vs[(vrow * 8 + (quad ^ (vrow & 7))) * 8]);
                bf16x8 v1 = *reinterpret_cast<const bf16x8*>(
                    &Vs[(vrow * 8 + ((4 + quad) ^ (vrow & 7))) * 8]);
                o[dt] = __builtin_amdgcn_mfma_f32_16x16x32_bf16(pf[0], v0, o[dt], 0, 0, 0);
                o[dt] = __builtin_amdgcn_mfma_f32_16x16x32_bf16(pf[1], v1, o[dt], 0, 0, 0);
            }
            __builtin_amdgcn_s_setprio(0);
        }

        // epilogue
#pragma unroll
        for (int r = 0; r < 4; r++) {
            float inv = 1.0f / lacc[r];
            int row = b * T_ + qlo + quad * 4 + r;
#pragma unroll
            for (int dt = 0; dt < 4; dt++)
                O[(size_t)row * D_MODEL + h * 64 + dt * 16 + l16] =
                    f2bf(o[dt][r] * inv);
        }
    }
}

extern "C" void kernel_launch(void* const* d_in, const int* in_sizes, int n_in,
                              void* d_out, int out_size, void* d_ws, size_t ws_size,
                              hipStream_t stream) {
    const float* x  = (const float*)d_in[0];
    const float* Wq = (const float*)d_in[1];
    const float* Wk = (const float*)d_in[2];
    const float* Wv = (const float*)d_in[3];
    const float* Wo = (const float*)d_in[4];

    unsigned short* xb   = (unsigned short*)d_ws;             // [4096][2048]
    unsigned short* Wqkv = xb + (size_t)BT * D_MODEL;         // [3072][2048]
    unsigned short* QKVo = Wqkv + (size_t)NQKV * D_MODEL;     // [4096][3072]
    unsigned short* Vt   = QKVo + (size_t)BT * NQKV;          // [16][64][2048]
    unsigned short* Aw   = xb;                                 // reuse after QKV GEMM
    unsigned short* Wob  = Wqkv;                               // reuse after QKV GEMM

    dim3 blk(256);
    cvt_all<<<dim3(14336), blk, 0, stream>>>(x, Wq, Wk, Wv, xb);
    // fused QKV projection; Q columns pre-scaled by 1/8*log2(e)
    gemm128<false, true><<<dim3(NQKV / 128, BT / 128), blk, 0, stream>>>(
        xb, Wqkv, QKVo, BT, NQKV, D_MODEL);
    cvt_bf16<<<dim3(D_MODEL * D_MODEL / 4 / 256), blk, 0, stream>>>(
        Wo, Wob, D_MODEL * D_MODEL / 4);
    vtrans<<<dim3(T_ / 64, B_ * N_KV), blk, 0, stream>>>(QKVo, Vt);
    attn7<<<dim3(8, B_ * N_HEADS), dim3(512), 0, stream>>>(QKVo, Vt, Aw);
    gemm128<true, false><<<dim3(D_MODEL / 128, BT / 128), blk, 0, stream>>>(
        Aw, Wob, d_out, BT, D_MODEL, D_MODEL);
}